// Round 4
// baseline (345.062 us; speedup 1.0000x reference)
//
#include <hip/hip_runtime.h>
#include <hip/hip_bf16.h>

typedef __bf16 bf16_t;
typedef __attribute__((ext_vector_type(8))) __bf16 bf16x8;
typedef __attribute__((ext_vector_type(4))) float f32x4;
typedef __attribute__((ext_vector_type(16))) float f32x16;

#define BH 64
#define KP 512
#define NN 4096
#define DD 64
#define GSZ (BH * KP * DD)  // offset of gV in d_out

#define MFMA16(a, b, c) __builtin_amdgcn_mfma_f32_16x16x32_bf16((a), (b), (c), 0, 0, 0)
#define MFMA32(a, b, c) __builtin_amdgcn_mfma_f32_32x32x16_bf16((a), (b), (c), 0, 0, 0)

__device__ __forceinline__ bf16x8 cvt8v(const f32x4 lo, const f32x4 hi) {
  bf16x8 r;
  r[0] = (bf16_t)lo[0]; r[1] = (bf16_t)lo[1]; r[2] = (bf16_t)lo[2]; r[3] = (bf16_t)lo[3];
  r[4] = (bf16_t)hi[0]; r[5] = (bf16_t)hi[1]; r[6] = (bf16_t)hi[2]; r[7] = (bf16_t)hi[3];
  return r;
}
__device__ __forceinline__ bf16x8 cvt8(const float* __restrict__ p) {
  return cvt8v(*(const f32x4*)p, *(const f32x4*)(p + 4));
}
__device__ __forceinline__ unsigned pack2(float a, float b) {
  union { bf16_t h[2]; unsigned u; } x;
  x.h[0] = (bf16_t)a; x.h[1] = (bf16_t)b;
  return x.u;
}

// global->LDS DMA, 16B per lane; lds dest is wave-uniform base + lane*16.
__device__ __forceinline__ void stage16(bf16_t* lds_base, const bf16_t* gsrc) {
  __builtin_amdgcn_global_load_lds(
      (const __attribute__((address_space(1))) void*)gsrc,
      (__attribute__((address_space(3))) void*)lds_base, 16, 0, 0);
}

// ---------------------------------------------------------------------------
// Prep (round-1 verbatim, proven): bf16 conversion + global transposes.
// ---------------------------------------------------------------------------
__global__ __launch_bounds__(256) void hop_prep(
    const float* __restrict__ xk, const float* __restrict__ xv,
    bf16_t* __restrict__ xk16, bf16_t* __restrict__ xkT16, bf16_t* __restrict__ xvT16)
{
  __shared__ __align__(16) bf16_t T[64 * 72];
  const int t = threadIdx.x;
  const int n0 = blockIdx.x * 64;
  const int bh = blockIdx.y;
  const int row = t >> 2;
  const int d0  = (t & 3) * 16;
  const int dcol = t >> 2;
  const int nb   = (t & 3) * 16;
  const size_t gb  = (size_t)bh * NN * DD;
  const size_t gbT = (size_t)bh * DD * NN;

  {
    const float* src = xk + gb + (size_t)(n0 + row) * DD + d0;
    const f32x4 a0 = *(const f32x4*)(src);
    const f32x4 a1 = *(const f32x4*)(src + 4);
    const f32x4 a2 = *(const f32x4*)(src + 8);
    const f32x4 a3 = *(const f32x4*)(src + 12);
    const bf16x8 lo = cvt8v(a0, a1), hi = cvt8v(a2, a3);
    bf16_t* dn = xk16 + gb + (size_t)(n0 + row) * DD + d0;
    *(bf16x8*)(dn)     = lo;
    *(bf16x8*)(dn + 8) = hi;
    *(bf16x8*)(T + row * 72 + d0)     = lo;
    *(bf16x8*)(T + row * 72 + d0 + 8) = hi;
  }
  __syncthreads();
  {
    bf16x8 o0, o1;
    #pragma unroll
    for (int j = 0; j < 8; j++) o0[j] = T[(nb + j) * 72 + dcol];
    #pragma unroll
    for (int j = 0; j < 8; j++) o1[j] = T[(nb + 8 + j) * 72 + dcol];
    bf16_t* dT = xkT16 + gbT + (size_t)dcol * NN + n0 + nb;
    *(bf16x8*)(dT)     = o0;
    *(bf16x8*)(dT + 8) = o1;
  }
  __syncthreads();
  {
    const float* src = xv + gb + (size_t)(n0 + row) * DD + d0;
    const f32x4 a0 = *(const f32x4*)(src);
    const f32x4 a1 = *(const f32x4*)(src + 4);
    const f32x4 a2 = *(const f32x4*)(src + 8);
    const f32x4 a3 = *(const f32x4*)(src + 12);
    *(bf16x8*)(T + row * 72 + d0)     = cvt8v(a0, a1);
    *(bf16x8*)(T + row * 72 + d0 + 8) = cvt8v(a2, a3);
  }
  __syncthreads();
  {
    bf16x8 o0, o1;
    #pragma unroll
    for (int j = 0; j < 8; j++) o0[j] = T[(nb + j) * 72 + dcol];
    #pragma unroll
    for (int j = 0; j < 8; j++) o1[j] = T[(nb + 8 + j) * 72 + dcol];
    bf16_t* dT = xvT16 + gbT + (size_t)dcol * NN + n0 + nb;
    *(bf16x8*)(dT)     = o0;
    *(bf16x8*)(dT + 8) = o1;
  }
}

// ---------------------------------------------------------------------------
// Pass 1 (round-1 verbatim, proven): inv_colsum[bh][n] = 1/sum_k exp(K.xk).
// ---------------------------------------------------------------------------
__global__ __launch_bounds__(256) void hop_pass1(
    const float* __restrict__ Km, const bf16_t* __restrict__ xk16,
    float* __restrict__ inv_colsum)
{
  __shared__ __align__(16) bf16_t Ks[128 * 72];

  const int tid  = threadIdx.x;
  const int wave = tid >> 6, lane = tid & 63;
  const int col  = lane & 15, quad = lane >> 4;
  const int bid  = blockIdx.x;
  const int bh   = (bid & 7) + 8 * ((bid >> 3) & 7);
  const int n0   = (bid >> 6) * 256 + wave * 64;

  const float*  Kb   = Km   + (size_t)bh * KP * DD;
  const bf16_t* xkb  = xk16 + (size_t)bh * NN * DD;

  bf16x8 bf[4][2];
  #pragma unroll
  for (int nsub = 0; nsub < 4; nsub++) {
    const bf16_t* p = xkb + (size_t)(n0 + nsub * 16 + col) * DD + quad * 8;
    bf[nsub][0] = *(const bf16x8*)(p);
    bf[nsub][1] = *(const bf16x8*)(p + 32);
  }

  float colacc[4] = {0.f, 0.f, 0.f, 0.f};
  const int srow = tid >> 1, sdo = (tid & 1) * 32;

  for (int kc = 0; kc < KP; kc += 128) {
    __syncthreads();
    const float* src = Kb + (size_t)(kc + srow) * DD + sdo;
    #pragma unroll
    for (int u = 0; u < 4; u++) {
      const f32x4 p0 = *(const f32x4*)(src + 8 * u);
      const f32x4 p1 = *(const f32x4*)(src + 8 * u + 4);
      *(bf16x8*)(Ks + srow * 72 + sdo + 8 * u) = cvt8v(p0, p1);
    }
    __syncthreads();
    #pragma unroll
    for (int ks = 0; ks < 8; ks++) {
      const bf16x8 a0 = *(const bf16x8*)(Ks + (ks * 16 + col) * 72 + quad * 8);
      const bf16x8 a1 = *(const bf16x8*)(Ks + (ks * 16 + col) * 72 + 32 + quad * 8);
      #pragma unroll
      for (int nsub = 0; nsub < 4; nsub++) {
        f32x4 c = {0.f, 0.f, 0.f, 0.f};
        c = MFMA16(a0, bf[nsub][0], c);
        c = MFMA16(a1, bf[nsub][1], c);
        colacc[nsub] += __expf(c[0]) + __expf(c[1]) + __expf(c[2]) + __expf(c[3]);
      }
    }
  }
  #pragma unroll
  for (int nsub = 0; nsub < 4; nsub++) {
    colacc[nsub] += __shfl_xor(colacc[nsub], 16, 64);
    colacc[nsub] += __shfl_xor(colacc[nsub], 32, 64);
  }
  float v = colacc[0];
  v = (quad == 1) ? colacc[1] : v;
  v = (quad == 2) ? colacc[2] : v;
  v = (quad == 3) ? colacc[3] : v;
  inv_colsum[bh * NN + n0 + quad * 16 + col] = 1.0f / v;
}

// ---------------------------------------------------------------------------
// Pass 2 (32x32 MFMA, occupancy-fixed): grid 512 = 64 bh x 8 k-blocks of 64.
// Wave w: k-group g=(w&1) (32 k), d-half dh=(w>>1) (32 d). Wave pairs (w,w+2)
// duplicate S/exp for their shared k-group (cheap; shortens per-wave chain)
// and each finishes a private 32k x 32d output tile + private rowsum -> no
// inter-wave epilogue comms. 2 WG/CU (8 waves) restores latency hiding.
// ---------------------------------------------------------------------------
#define NT 64

__global__ __launch_bounds__(256) void hop_pass2(
    const float* __restrict__ Km, const float* __restrict__ Vm,
    const bf16_t* __restrict__ xk16, const bf16_t* __restrict__ xkT16,
    const bf16_t* __restrict__ xvT16,
    const float* __restrict__ inv_colsum, float* __restrict__ out)
{
  __shared__ __align__(16) bf16_t xks[2][NT * DD];  // [n][d] (blocks swizzled)
  __shared__ __align__(16) bf16_t xkT[2][DD * NT];  // [d][n]
  __shared__ __align__(16) bf16_t xvT[2][DD * NT];
  __shared__ float rows_lds[4][32];

  const int tid  = threadIdx.x;
  const int wave = tid >> 6, lane = tid & 63;
  const int col  = lane & 31, hi = lane >> 5;
  const int bid  = blockIdx.x;
  const int bh   = (bid & 7) + 8 * ((bid >> 3) & 7);  // same-bh blocks -> same XCD
  const int kblk = bid >> 6;                          // 0..7
  const int k0w  = kblk * 64 + (wave & 1) * 32;       // wave's 32 k-rows
  const int dh   = wave >> 1;                         // wave's d-half (0,1)

  const float*  Kb   = Km    + (size_t)bh * KP * DD;
  const float*  Vb   = Vm    + (size_t)bh * KP * DD;
  const bf16_t* xkb  = xk16  + (size_t)bh * NN * DD;
  const bf16_t* xkTb = xkT16 + (size_t)bh * DD * NN;
  const bf16_t* xvTb = xvT16 + (size_t)bh * DD * NN;
  const float*  inv  = inv_colsum + bh * NN;

  // K fragments (MFMA B-operand for S): bk[t] elem j = K[k0w+col][t*16+hi*8+j]
  bf16x8 bk[4];
  #pragma unroll
  for (int t = 0; t < 4; t++)
    bk[t] = cvt8(Kb + (size_t)(k0w + col) * DD + t * 16 + hi * 8);

  f32x16 accK, accV;
  #pragma unroll
  for (int r = 0; r < 16; r++) { accK[r] = 0.f; accV[r] = 0.f; }
  float rowacc = 0.f;

  // staging geometry: chunk rows wave*16 + c*8 + (lane>>3), 16B-block (lane&7),
  // source block pre-XORed by row&7 (LDS[row][slot] = global[row][slot^(row&7)]).
  const int srl = lane >> 3;
  const int r0  = wave * 16 + srl;
  const int r1  = r0 + 8;
  const int sb  = ((lane & 7) ^ srl) * 8;
  const int lb0 = (wave * 2 + 0) * 512;
  const int lb1 = (wave * 2 + 1) * 512;

  stage16(&xks[0][lb0], xkb + (size_t)r0 * DD + sb);
  stage16(&xks[0][lb1], xkb + (size_t)r1 * DD + sb);
  stage16(&xkT[0][lb0], xkTb + (size_t)r0 * NN + sb);
  stage16(&xkT[0][lb1], xkTb + (size_t)r1 * NN + sb);
  stage16(&xvT[0][lb0], xvTb + (size_t)r0 * NN + sb);
  stage16(&xvT[0][lb1], xvTb + (size_t)r1 * NN + sb);
  __syncthreads();

  int cur = 0;
  for (int n0 = 0; n0 < NN; n0 += NT) {
    if (n0 + NT < NN) {
      const int nx = n0 + NT;
      const int nb2 = cur ^ 1;
      stage16(&xks[nb2][lb0], xkb + (size_t)(nx + r0) * DD + sb);
      stage16(&xks[nb2][lb1], xkb + (size_t)(nx + r1) * DD + sb);
      stage16(&xkT[nb2][lb0], xkTb + (size_t)r0 * NN + nx + sb);
      stage16(&xkT[nb2][lb1], xkTb + (size_t)r1 * NN + nx + sb);
      stage16(&xvT[nb2][lb0], xvTb + (size_t)r0 * NN + nx + sb);
      stage16(&xvT[nb2][lb1], xvTb + (size_t)r1 * NN + nx + sb);
    }

    const bf16_t* xs = xks[cur];
    bf16x8 wa[4];  // w A-frags: wa[c] elem j = w[k=k0w+col][n0 + c*16 + hi*8 + j]

    #pragma unroll
    for (int nh = 0; nh < 2; nh++) {
      // icv[q][e] = inv[n0 + 32*nh + 8*q + 4*hi + e]
      f32x4 icv[4];
      #pragma unroll
      for (int q = 0; q < 4; q++)
        icv[q] = *(const f32x4*)(inv + n0 + 32 * nh + 8 * q + 4 * hi);

      // S' = xk . K^T: C[n][k], lane holds n-rows {(r&3)+8(r>>2)+4hi}, k=k0w+col
      const int n  = nh * 32 + col;
      const int rb = n * DD;
      f32x16 s;
      #pragma unroll
      for (int r = 0; r < 16; r++) s[r] = 0.f;
      #pragma unroll
      for (int t = 0; t < 4; t++) {
        const bf16x8 a = *(const bf16x8*)(xs + rb + (((2 * t + hi) ^ (n & 7)) << 3));
        s = MFMA32(a, bk[t], s);
      }
      // w = exp(S)*ic; redistribute C[n][k] -> A[k][n] frags via permlane32_swap
      #pragma unroll
      for (int b = 0; b < 2; b++) {
        float p[8];
        #pragma unroll
        for (int j = 0; j < 8; j++)
          p[j] = __expf(s[8 * b + j]) * icv[2 * b + (j >> 2)][j & 3];
        rowacc += ((p[0] + p[1]) + (p[2] + p[3])) + ((p[4] + p[5]) + (p[6] + p[7]));
        unsigned q0a = pack2(p[0], p[1]), q0b = pack2(p[2], p[3]);
        unsigned q1a = pack2(p[4], p[5]), q1b = pack2(p[6], p[7]);
        asm("v_permlane32_swap_b32 %0, %1" : "+v"(q0a), "+v"(q1a));
        asm("v_permlane32_swap_b32 %0, %1" : "+v"(q0b), "+v"(q1b));
        union { unsigned u[4]; bf16x8 v; } f;
        f.u[0] = q0a; f.u[1] = q0b; f.u[2] = q1a; f.u[3] = q1b;
        wa[nh * 2 + b] = f.v;
      }
    }

    // PV for this wave's d-half only: acc[k][d] += w . x
    {
      const int d   = dh * 32 + col;
      const int rbd = d * NT;
      const bf16_t* kp = xkT[cur];
      const bf16_t* vp = xvT[cur];
      #pragma unroll
      for (int c = 0; c < 4; c++) {
        const int off = rbd + (((2 * c + hi) ^ (d & 7)) << 3);
        const bf16x8 bkf = *(const bf16x8*)(kp + off);
        const bf16x8 bvf = *(const bf16x8*)(vp + off);
        accK = MFMA32(wa[c], bkf, accK);
        accV = MFMA32(wa[c], bvf, accV);
      }
    }

    __syncthreads();
    cur ^= 1;
  }

  // rowsum for k = k0w+col (lane holds half the n's; combine hi-halves)
  rowacc += __shfl_xor(rowacc, 32, 64);
  rows_lds[wave][col] = 1.0f / rowacc;  // both halves write same value
  // same-wave LDS write->read: lgkmcnt ordering suffices (private table)

  // epilogue: acc C layout row kw = (r&3)+8*(r>>2)+4*hi, col d = dh*32+col
  const size_t base = (size_t)bh * KP * DD;
  #pragma unroll
  for (int r = 0; r < 16; r++) {
    const int kw = (r & 3) + 8 * (r >> 2) + 4 * hi;
    const float invr = rows_lds[wave][kw];
    const int k = k0w + kw;
    const int d = dh * 32 + col;
    const size_t idx = base + (size_t)k * DD + d;
    out[idx]       = accK[r] * invr - Kb[(size_t)k * DD + d];
    out[GSZ + idx] = accV[r] * invr - Vb[(size_t)k * DD + d];
  }
}

// ---------------------------------------------------------------------------
// Fallback path (ws too small for bf16 scratch): round-0 verified kernels.
// ---------------------------------------------------------------------------
#define PW 72

__global__ __launch_bounds__(256) void hop_pass1_fb(
    const float* __restrict__ Km, const float* __restrict__ xk,
    float* __restrict__ inv_colsum)
{
  __shared__ __align__(16) bf16_t Ks[128 * 72];
  const int tid  = threadIdx.x;
  const int wave = tid >> 6, lane = tid & 63;
  const int col  = lane & 15, quad = lane >> 4;
  const int bh = blockIdx.y;
  const int n0 = blockIdx.x * 256 + wave * 64;
  const float* Kb  = Km + (size_t)bh * KP * DD;
  const float* xkb = xk + (size_t)bh * NN * DD;
  bf16x8 bf[4][2];
  #pragma unroll
  for (int nsub = 0; nsub < 4; nsub++) {
    const float* p = xkb + (size_t)(n0 + nsub * 16 + col) * DD + quad * 8;
    bf[nsub][0] = cvt8(p);
    bf[nsub][1] = cvt8(p + 32);
  }
  float colacc[4] = {0.f, 0.f, 0.f, 0.f};
  const int srow = tid >> 1, sdo = (tid & 1) * 32;
  for (int kc = 0; kc < KP; kc += 128) {
    __syncthreads();
    const float* src = Kb + (size_t)(kc + srow) * DD + sdo;
    #pragma unroll
    for (int u = 0; u < 4; u++) {
      const f32x4 p0 = *(const f32x4*)(src + 8 * u);
      const f32x4 p1 = *(const f32x4*)(src + 8 * u + 4);
      *(bf16x8*)(Ks + srow * 72 + sdo + 8 * u) = cvt8v(p0, p1);
    }
    __syncthreads();
    #pragma unroll
    for (int ks = 0; ks < 8; ks++) {
      const bf16x8 a0 = *(const bf16x8*)(Ks + (ks * 16 + col) * 72 + quad * 8);
      const bf16x8 a1 = *(const bf16x8*)(Ks + (ks * 16 + col) * 72 + 32 + quad * 8);
      #pragma unroll
      for (int nsub = 0; nsub < 4; nsub++) {
        f32x4 c = {0.f, 0.f, 0.f, 0.f};
        c = MFMA16(a0, bf[nsub][0], c);
        c = MFMA16(a1, bf[nsub][1], c);
        colacc[nsub] += __expf(c[0]) + __expf(c[1]) + __expf(c[2]) + __expf(c[3]);
      }
    }
  }
  #pragma unroll
  for (int nsub = 0; nsub < 4; nsub++) {
    colacc[nsub] += __shfl_xor(colacc[nsub], 16, 64);
    colacc[nsub] += __shfl_xor(colacc[nsub], 32, 64);
  }
  float v = colacc[0];
  v = (quad == 1) ? colacc[1] : v;
  v = (quad == 2) ? colacc[2] : v;
  v = (quad == 3) ? colacc[3] : v;
  inv_colsum[bh * NN + n0 + quad * 16 + col] = 1.0f / v;
}

__global__ __launch_bounds__(256) void hop_pass2_fb(
    const float* __restrict__ Km, const float* __restrict__ Vm,
    const float* __restrict__ xk, const float* __restrict__ xv,
    const float* __restrict__ inv_colsum, float* __restrict__ out)
{
  __shared__ __align__(16) bf16_t xksf[NT * PW];
  __shared__ __align__(16) bf16_t xkTf[DD * NT];
  __shared__ __align__(16) bf16_t xvTf[DD * NT];
  __shared__ __align__(16) bf16_t wtf[4][16 * PW];

  const int tid  = threadIdx.x;
  const int wave = tid >> 6, lane = tid & 63;
  const int col  = lane & 15, quad = lane >> 4;
  const int bh   = blockIdx.x >> 3;
  const int k0   = (blockIdx.x & 7) * 64 + wave * 16;

  const float* Kb  = Km + (size_t)bh * KP * DD;
  const float* Vb  = Vm + (size_t)bh * KP * DD;
  const float* xkb = xk + (size_t)bh * NN * DD;
  const float* xvb = xv + (size_t)bh * NN * DD;
  const float* inv = inv_colsum + bh * NN;

  const bf16x8 ak0 = cvt8(Kb + (size_t)(k0 + col) * DD + quad * 8);
  const bf16x8 ak1 = cvt8(Kb + (size_t)(k0 + col) * DD + 32 + quad * 8);

  f32x4 accK[4], accV[4];
  #pragma unroll
  for (int i = 0; i < 4; i++) {
    accK[i] = (f32x4){0.f, 0.f, 0.f, 0.f};
    accV[i] = (f32x4){0.f, 0.f, 0.f, 0.f};
  }
  float rows_part = 0.f;

  const int sn = tid >> 2;
  const int sd = (tid & 3) * 16;
  const int shi = sn >> 3, slo = sn & 7;

  for (int n0 = 0; n0 < NN; n0 += NT) {
    f32x4 gk[4], gv[4];
    #pragma unroll
    for (int u = 0; u < 4; u++) {
      gk[u] = *(const f32x4*)(xkb + (size_t)(n0 + sn) * DD + sd + 4 * u);
      gv[u] = *(const f32x4*)(xvb + (size_t)(n0 + sn) * DD + sd + 4 * u);
    }
    float ic[4];
    #pragma unroll
    for (int nsub = 0; nsub < 4; nsub++) ic[nsub] = inv[n0 + nsub * 16 + col];

    __syncthreads();
    *(bf16x8*)(xksf + sn * PW + sd)     = cvt8v(gk[0], gk[1]);
    *(bf16x8*)(xksf + sn * PW + sd + 8) = cvt8v(gk[2], gk[3]);
    #pragma unroll
    for (int j = 0; j < 16; j++) {
      const int d   = sd + j;
      const int off = d * NT + (((shi) ^ (d >> 3)) << 3) + slo;
      xkTf[off] = (bf16_t)gk[j >> 2][j & 3];
      xvTf[off] = (bf16_t)gv[j >> 2][j & 3];
    }
    __syncthreads();

    f32x4 s[4];
    #pragma unroll
    for (int nsub = 0; nsub < 4; nsub++) {
      const bf16x8 b0 = *(const bf16x8*)(xksf + (nsub * 16 + col) * PW + quad * 8);
      const bf16x8 b1 = *(const bf16x8*)(xksf + (nsub * 16 + col) * PW + 32 + quad * 8);
      f32x4 c = {0.f, 0.f, 0.f, 0.f};
      c = MFMA16(ak0, b0, c);
      c = MFMA16(ak1, b1, c);
      s[nsub] = c;
    }
    bf16_t* wr = wtf[wave];
    #pragma unroll
    for (int nsub = 0; nsub < 4; nsub++) {
      #pragma unroll
      for (int r = 0; r < 4; r++)
        wr[(quad * 4 + r) * PW + nsub * 16 + col] = (bf16_t)(__expf(s[nsub][r]) * ic[nsub]);
    }
    const bf16x8 wa0 = *(const bf16x8*)(wr + col * PW + quad * 8);
    const bf16x8 wa1 = *(const bf16x8*)(wr + col * PW + 32 + quad * 8);
    #pragma unroll
    for (int j = 0; j < 8; j++) rows_part += (float)wa0[j] + (float)wa1[j];

    #pragma unroll
    for (int dt = 0; dt < 4; dt++) {
      const int d = dt * 16 + col, dhi = d >> 3;
      const bf16x8 bk0 = *(const bf16x8*)(xkTf + d * NT + ((quad ^ dhi) << 3));
      const bf16x8 bk1 = *(const bf16x8*)(xkTf + d * NT + (((4 + quad) ^ dhi) << 3));
      const bf16x8 bv0 = *(const bf16x8*)(xvTf + d * NT + ((quad ^ dhi) << 3));
      const bf16x8 bv1 = *(const bf16x8*)(xvTf + d * NT + (((4 + quad) ^ dhi) << 3));
      accK[dt] = MFMA16(wa0, bk0, accK[dt]);
      accK[dt] = MFMA16(wa1, bk1, accK[dt]);
      accV[dt] = MFMA16(wa0, bv0, accV[dt]);
      accV[dt] = MFMA16(wa1, bv1, accV[dt]);
    }
  }

  float rs = rows_part;
  rs += __shfl_xor(rs, 16, 64);
  rs += __shfl_xor(rs, 32, 64);
  float invrs[4];
  #pragma unroll
  for (int r = 0; r < 4; r++) invrs[r] = 1.0f / __shfl(rs, quad * 4 + r, 64);

  const size_t base = (size_t)bh * KP * DD;
  #pragma unroll
  for (int dt = 0; dt < 4; dt++) {
    #pragma unroll
    for (int r = 0; r < 4; r++) {
      const int k = k0 + quad * 4 + r;
      const int d = dt * 16 + col;
      const size_t idx = base + (size_t)k * DD + d;
      out[idx]       = accK[dt][r] * invrs[r] - Kb[(size_t)k * DD + d];
      out[GSZ + idx] = accV[dt][r] * invrs[r] - Vb[(size_t)k * DD + d];
    }
  }
}

extern "C" void kernel_launch(void* const* d_in, const int* in_sizes, int n_in,
                              void* d_out, int out_size, void* d_ws, size_t ws_size,
                              hipStream_t stream)
{
  (void)in_sizes; (void)n_in; (void)out_size;
  const float* Km = (const float*)d_in[0];
  const float* Vm = (const float*)d_in[1];
  const float* xk = (const float*)d_in[2];
  const float* xv = (const float*)d_in[3];
  float* out = (float*)d_out;
  float* inv_colsum = (float*)d_ws;  // BH*NN floats = 1 MB

  const size_t SCRE = (size_t)BH * NN * DD;  // elems per bf16 scratch array
  const size_t NEED = (size_t)BH * NN * sizeof(float) + 3 * SCRE * sizeof(bf16_t);

  if (ws_size >= NEED) {
    bf16_t* xk16  = (bf16_t*)((char*)d_ws + (size_t)BH * NN * sizeof(float));
    bf16_t* xkT16 = xk16 + SCRE;
    bf16_t* xvT16 = xkT16 + SCRE;
    hop_prep<<<dim3(NN / 64, BH), 256, 0, stream>>>(xk, xv, xk16, xkT16, xvT16);
    hop_pass1<<<dim3((NN / 256) * BH), 256, 0, stream>>>(Km, xk16, inv_colsum);
    hop_pass2<<<dim3(BH * 8), 256, 0, stream>>>(Km, Vm, xk16, xkT16, xvT16,
                                                inv_colsum, out);
  } else {
    hop_pass1_fb<<<dim3(NN / 256, BH), 256, 0, stream>>>(Km, xk, inv_colsum);
    hop_pass2_fb<<<dim3(BH * (KP / 64)), 256, 0, stream>>>(Km, Vm, xk, xv,
                                                           inv_colsum, out);
  }
}

// Round 5
// 303.314 us; speedup vs baseline: 1.1376x; 1.1376x over previous
//
#include <hip/hip_runtime.h>
#include <hip/hip_bf16.h>

typedef __bf16 bf16_t;
typedef __attribute__((ext_vector_type(8))) __bf16 bf16x8;
typedef __attribute__((ext_vector_type(4))) float f32x4;
typedef __attribute__((ext_vector_type(16))) float f32x16;

#define BH 64
#define KP 512
#define NN 4096
#define DD 64
#define GSZ (BH * KP * DD)  // offset of gV in d_out
#define NT 64
#define NHALF 2048

#define MFMA16(a, b, c) __builtin_amdgcn_mfma_f32_16x16x32_bf16((a), (b), (c), 0, 0, 0)
#define MFMA32(a, b, c) __builtin_amdgcn_mfma_f32_32x32x16_bf16((a), (b), (c), 0, 0, 0)

__device__ __forceinline__ bf16x8 cvt8v(const f32x4 lo, const f32x4 hi) {
  bf16x8 r;
  r[0] = (bf16_t)lo[0]; r[1] = (bf16_t)lo[1]; r[2] = (bf16_t)lo[2]; r[3] = (bf16_t)lo[3];
  r[4] = (bf16_t)hi[0]; r[5] = (bf16_t)hi[1]; r[6] = (bf16_t)hi[2]; r[7] = (bf16_t)hi[3];
  return r;
}
__device__ __forceinline__ bf16x8 cvt8(const float* __restrict__ p) {
  return cvt8v(*(const f32x4*)p, *(const f32x4*)(p + 4));
}
__device__ __forceinline__ unsigned pack2(float a, float b) {
  union { bf16_t h[2]; unsigned u; } x;
  x.h[0] = (bf16_t)a; x.h[1] = (bf16_t)b;
  return x.u;
}

// global->LDS DMA, 16B per lane; lds dest is wave-uniform base + lane*16.
__device__ __forceinline__ void stage16(bf16_t* lds_base, const bf16_t* gsrc) {
  __builtin_amdgcn_global_load_lds(
      (const __attribute__((address_space(1))) void*)gsrc,
      (__attribute__((address_space(3))) void*)lds_base, 16, 0, 0);
}

// ---------------------------------------------------------------------------
// Prep (round-1 verbatim, proven): bf16 conversion + global transposes.
// ---------------------------------------------------------------------------
__global__ __launch_bounds__(256) void hop_prep(
    const float* __restrict__ xk, const float* __restrict__ xv,
    bf16_t* __restrict__ xk16, bf16_t* __restrict__ xkT16, bf16_t* __restrict__ xvT16)
{
  __shared__ __align__(16) bf16_t T[64 * 72];
  const int t = threadIdx.x;
  const int n0 = blockIdx.x * 64;
  const int bh = blockIdx.y;
  const int row = t >> 2;
  const int d0  = (t & 3) * 16;
  const int dcol = t >> 2;
  const int nb   = (t & 3) * 16;
  const size_t gb  = (size_t)bh * NN * DD;
  const size_t gbT = (size_t)bh * DD * NN;

  {
    const float* src = xk + gb + (size_t)(n0 + row) * DD + d0;
    const f32x4 a0 = *(const f32x4*)(src);
    const f32x4 a1 = *(const f32x4*)(src + 4);
    const f32x4 a2 = *(const f32x4*)(src + 8);
    const f32x4 a3 = *(const f32x4*)(src + 12);
    const bf16x8 lo = cvt8v(a0, a1), hi = cvt8v(a2, a3);
    bf16_t* dn = xk16 + gb + (size_t)(n0 + row) * DD + d0;
    *(bf16x8*)(dn)     = lo;
    *(bf16x8*)(dn + 8) = hi;
    *(bf16x8*)(T + row * 72 + d0)     = lo;
    *(bf16x8*)(T + row * 72 + d0 + 8) = hi;
  }
  __syncthreads();
  {
    bf16x8 o0, o1;
    #pragma unroll
    for (int j = 0; j < 8; j++) o0[j] = T[(nb + j) * 72 + dcol];
    #pragma unroll
    for (int j = 0; j < 8; j++) o1[j] = T[(nb + 8 + j) * 72 + dcol];
    bf16_t* dT = xkT16 + gbT + (size_t)dcol * NN + n0 + nb;
    *(bf16x8*)(dT)     = o0;
    *(bf16x8*)(dT + 8) = o1;
  }
  __syncthreads();
  {
    const float* src = xv + gb + (size_t)(n0 + row) * DD + d0;
    const f32x4 a0 = *(const f32x4*)(src);
    const f32x4 a1 = *(const f32x4*)(src + 4);
    const f32x4 a2 = *(const f32x4*)(src + 8);
    const f32x4 a3 = *(const f32x4*)(src + 12);
    *(bf16x8*)(T + row * 72 + d0)     = cvt8v(a0, a1);
    *(bf16x8*)(T + row * 72 + d0 + 8) = cvt8v(a2, a3);
  }
  __syncthreads();
  {
    bf16x8 o0, o1;
    #pragma unroll
    for (int j = 0; j < 8; j++) o0[j] = T[(nb + j) * 72 + dcol];
    #pragma unroll
    for (int j = 0; j < 8; j++) o1[j] = T[(nb + 8 + j) * 72 + dcol];
    bf16_t* dT = xvT16 + gbT + (size_t)dcol * NN + n0 + nb;
    *(bf16x8*)(dT)     = o0;
    *(bf16x8*)(dT + 8) = o1;
  }
}

// ---------------------------------------------------------------------------
// Pass 1 (round-1 verbatim, proven): inv_colsum[bh][n] = 1/sum_k exp(K.xk).
// ---------------------------------------------------------------------------
__global__ __launch_bounds__(256) void hop_pass1(
    const float* __restrict__ Km, const bf16_t* __restrict__ xk16,
    float* __restrict__ inv_colsum)
{
  __shared__ __align__(16) bf16_t Ks[128 * 72];

  const int tid  = threadIdx.x;
  const int wave = tid >> 6, lane = tid & 63;
  const int col  = lane & 15, quad = lane >> 4;
  const int bid  = blockIdx.x;
  const int bh   = (bid & 7) + 8 * ((bid >> 3) & 7);
  const int n0   = (bid >> 6) * 256 + wave * 64;

  const float*  Kb   = Km   + (size_t)bh * KP * DD;
  const bf16_t* xkb  = xk16 + (size_t)bh * NN * DD;

  bf16x8 bf[4][2];
  #pragma unroll
  for (int nsub = 0; nsub < 4; nsub++) {
    const bf16_t* p = xkb + (size_t)(n0 + nsub * 16 + col) * DD + quad * 8;
    bf[nsub][0] = *(const bf16x8*)(p);
    bf[nsub][1] = *(const bf16x8*)(p + 32);
  }

  float colacc[4] = {0.f, 0.f, 0.f, 0.f};
  const int srow = tid >> 1, sdo = (tid & 1) * 32;

  for (int kc = 0; kc < KP; kc += 128) {
    __syncthreads();
    const float* src = Kb + (size_t)(kc + srow) * DD + sdo;
    #pragma unroll
    for (int u = 0; u < 4; u++) {
      const f32x4 p0 = *(const f32x4*)(src + 8 * u);
      const f32x4 p1 = *(const f32x4*)(src + 8 * u + 4);
      *(bf16x8*)(Ks + srow * 72 + sdo + 8 * u) = cvt8v(p0, p1);
    }
    __syncthreads();
    #pragma unroll
    for (int ks = 0; ks < 8; ks++) {
      const bf16x8 a0 = *(const bf16x8*)(Ks + (ks * 16 + col) * 72 + quad * 8);
      const bf16x8 a1 = *(const bf16x8*)(Ks + (ks * 16 + col) * 72 + 32 + quad * 8);
      #pragma unroll
      for (int nsub = 0; nsub < 4; nsub++) {
        f32x4 c = {0.f, 0.f, 0.f, 0.f};
        c = MFMA16(a0, bf[nsub][0], c);
        c = MFMA16(a1, bf[nsub][1], c);
        colacc[nsub] += __expf(c[0]) + __expf(c[1]) + __expf(c[2]) + __expf(c[3]);
      }
    }
  }
  #pragma unroll
  for (int nsub = 0; nsub < 4; nsub++) {
    colacc[nsub] += __shfl_xor(colacc[nsub], 16, 64);
    colacc[nsub] += __shfl_xor(colacc[nsub], 32, 64);
  }
  float v = colacc[0];
  v = (quad == 1) ? colacc[1] : v;
  v = (quad == 2) ? colacc[2] : v;
  v = (quad == 3) ? colacc[3] : v;
  inv_colsum[bh * NN + n0 + quad * 16 + col] = 1.0f / v;
}

// ---------------------------------------------------------------------------
// Pass 2 split (32x32 MFMA, r3 math, n-halved): grid 512 = 64bh x 4ktile x
// 2 n-halves. Block = 4 waves x 32k = 128k over 2048 n (32 iters). No S/exp
// duplication; 2 blocks/CU restores latency hiding. Writes f32 partial
// accumulators + partial rowsums; hop_fin combines.
// ---------------------------------------------------------------------------
__global__ __launch_bounds__(256) void hop_pass2s(
    const float* __restrict__ Km,
    const bf16_t* __restrict__ xk16, const bf16_t* __restrict__ xkT16,
    const bf16_t* __restrict__ xvT16,
    const float* __restrict__ inv_colsum,
    float* __restrict__ pK, float* __restrict__ pV, float* __restrict__ prs)
{
  __shared__ __align__(16) bf16_t xks[2][NT * DD];  // [n][d] (blocks swizzled)
  __shared__ __align__(16) bf16_t xkT[2][DD * NT];  // [d][n]
  __shared__ __align__(16) bf16_t xvT[2][DD * NT];

  const int tid  = threadIdx.x;
  const int wave = tid >> 6, lane = tid & 63;
  const int col  = lane & 31, hi = lane >> 5;
  const int bid  = blockIdx.x;
  const int bh   = (bid & 7) + 8 * ((bid >> 3) & 7);  // same-bh blocks -> same XCD
  const int sub  = bid >> 6;                          // 0..7
  const int kblk = sub & 3;
  const int nh   = sub >> 2;                          // n-half 0/1
  const int k0w  = kblk * 128 + wave * 32;            // wave's 32 k-rows
  const int nbase = nh * NHALF;

  const float*  Kb   = Km    + (size_t)bh * KP * DD;
  const bf16_t* xkb  = xk16  + (size_t)bh * NN * DD;
  const bf16_t* xkTb = xkT16 + (size_t)bh * DD * NN;
  const bf16_t* xvTb = xvT16 + (size_t)bh * DD * NN;
  const float*  inv  = inv_colsum + bh * NN;

  // K fragments (MFMA B-operand for S): bk[t] elem j = K[k0w+col][t*16+hi*8+j]
  bf16x8 bk[4];
  #pragma unroll
  for (int t = 0; t < 4; t++)
    bk[t] = cvt8(Kb + (size_t)(k0w + col) * DD + t * 16 + hi * 8);

  f32x16 accK[2], accV[2];
  #pragma unroll
  for (int i = 0; i < 2; i++) {
    #pragma unroll
    for (int r = 0; r < 16; r++) { accK[i][r] = 0.f; accV[i][r] = 0.f; }
  }
  float rowacc = 0.f;

  // staging: chunk rows wave*16 + c*8 + (lane>>3), 16B-block (lane&7),
  // source block pre-XORed by row&7 (LDS[row][slot] = global[row][slot^(row&7)]).
  const int srl = lane >> 3;
  const int r0  = wave * 16 + srl;
  const int r1  = r0 + 8;
  const int sb  = ((lane & 7) ^ srl) * 8;
  const int lb0 = (wave * 2 + 0) * 512;
  const int lb1 = (wave * 2 + 1) * 512;

  stage16(&xks[0][lb0], xkb + (size_t)(nbase + r0) * DD + sb);
  stage16(&xks[0][lb1], xkb + (size_t)(nbase + r1) * DD + sb);
  stage16(&xkT[0][lb0], xkTb + (size_t)r0 * NN + nbase + sb);
  stage16(&xkT[0][lb1], xkTb + (size_t)r1 * NN + nbase + sb);
  stage16(&xvT[0][lb0], xvTb + (size_t)r0 * NN + nbase + sb);
  stage16(&xvT[0][lb1], xvTb + (size_t)r1 * NN + nbase + sb);
  __syncthreads();

  int cur = 0;
  for (int n0 = nbase; n0 < nbase + NHALF; n0 += NT) {
    if (n0 + NT < nbase + NHALF) {
      const int nx = n0 + NT;
      const int nb2 = cur ^ 1;
      stage16(&xks[nb2][lb0], xkb + (size_t)(nx + r0) * DD + sb);
      stage16(&xks[nb2][lb1], xkb + (size_t)(nx + r1) * DD + sb);
      stage16(&xkT[nb2][lb0], xkTb + (size_t)r0 * NN + nx + sb);
      stage16(&xkT[nb2][lb1], xkTb + (size_t)r1 * NN + nx + sb);
      stage16(&xvT[nb2][lb0], xvTb + (size_t)r0 * NN + nx + sb);
      stage16(&xvT[nb2][lb1], xvTb + (size_t)r1 * NN + nx + sb);
    }

    const bf16_t* xs = xks[cur];
    bf16x8 wa[4];  // w A-frags: wa[c] elem j = w[k=k0w+col][n0 + c*16 + hi*8 + j]

    #pragma unroll
    for (int g = 0; g < 2; g++) {
      // icv[q][e] = inv[n0 + 32*g + 8*q + 4*hi + e]
      f32x4 icv[4];
      #pragma unroll
      for (int q = 0; q < 4; q++)
        icv[q] = *(const f32x4*)(inv + n0 + 32 * g + 8 * q + 4 * hi);

      // S' = xk . K^T: C[n][k], lane holds n-rows {(r&3)+8(r>>2)+4hi}, k=k0w+col
      const int n  = g * 32 + col;
      const int rb = n * DD;
      f32x16 s;
      #pragma unroll
      for (int r = 0; r < 16; r++) s[r] = 0.f;
      #pragma unroll
      for (int t = 0; t < 4; t++) {
        const bf16x8 a = *(const bf16x8*)(xs + rb + (((2 * t + hi) ^ (n & 7)) << 3));
        s = MFMA32(a, bk[t], s);
      }
      // w = exp(S)*ic; redistribute C[n][k] -> A[k][n] frags via permlane32_swap
      #pragma unroll
      for (int b = 0; b < 2; b++) {
        float p[8];
        #pragma unroll
        for (int j = 0; j < 8; j++)
          p[j] = __expf(s[8 * b + j]) * icv[2 * b + (j >> 2)][j & 3];
        rowacc += ((p[0] + p[1]) + (p[2] + p[3])) + ((p[4] + p[5]) + (p[6] + p[7]));
        unsigned q0a = pack2(p[0], p[1]), q0b = pack2(p[2], p[3]);
        unsigned q1a = pack2(p[4], p[5]), q1b = pack2(p[6], p[7]);
        asm("v_permlane32_swap_b32 %0, %1" : "+v"(q0a), "+v"(q1a));
        asm("v_permlane32_swap_b32 %0, %1" : "+v"(q0b), "+v"(q1b));
        union { unsigned u[4]; bf16x8 v; } f;
        f.u[0] = q0a; f.u[1] = q0b; f.u[2] = q1a; f.u[3] = q1b;
        wa[g * 2 + b] = f.v;
      }
    }

    // PV: acc[k][d] += w . x  (A = wa[c] covers kk = n chunk c)
    #pragma unroll
    for (int dg = 0; dg < 2; dg++) {
      const int d   = dg * 32 + col;
      const int rbd = d * NT;
      const bf16_t* kp = xkT[cur];
      const bf16_t* vp = xvT[cur];
      #pragma unroll
      for (int c = 0; c < 4; c++) {
        const int off = rbd + (((2 * c + hi) ^ (d & 7)) << 3);
        const bf16x8 bkf = *(const bf16x8*)(kp + off);
        const bf16x8 bvf = *(const bf16x8*)(vp + off);
        accK[dg] = MFMA32(wa[c], bkf, accK[dg]);
        accV[dg] = MFMA32(wa[c], bvf, accV[dg]);
      }
    }

    __syncthreads();
    cur ^= 1;
  }

  // partial rowsum for k = k0w+col (combine hi-halves; hi==0 writes)
  rowacc += __shfl_xor(rowacc, 32, 64);
  if (hi == 0) prs[((size_t)nh * BH + bh) * KP + k0w + col] = rowacc;

  // partial accumulators: [nh][bh][k][d] f32
  float* pKb = pK + ((size_t)(nh * BH + bh) * KP) * DD;
  float* pVb = pV + ((size_t)(nh * BH + bh) * KP) * DD;
  #pragma unroll
  for (int dg = 0; dg < 2; dg++) {
    #pragma unroll
    for (int r = 0; r < 16; r++) {
      const int kw = (r & 3) + 8 * (r >> 2) + 4 * hi;
      const int k = k0w + kw;
      const int d = dg * 32 + col;
      pKb[(size_t)k * DD + d] = accK[dg][r];
      pVb[(size_t)k * DD + d] = accV[dg][r];
    }
  }
}

// ---------------------------------------------------------------------------
// Finish: out = (P0+P1)/rowsum - K (and V). Pure BW (~64MB). Grid 1024x256.
// ---------------------------------------------------------------------------
__global__ __launch_bounds__(256) void hop_fin(
    const float* __restrict__ Km, const float* __restrict__ Vm,
    const float* __restrict__ pK, const float* __restrict__ pV,
    const float* __restrict__ prs, float* __restrict__ out)
{
  const int t = blockIdx.x * 256 + threadIdx.x;
  const size_t e  = (size_t)t * 8;          // flat [bh][k][d] elem, 8 per thread
  const size_t kk = e >> 6;                 // bh*KP + k
  const size_t off = e;                     // == kk*DD + d0
  const size_t plane = (size_t)BH * KP * DD;

  const float invr = 1.0f / (prs[kk] + prs[(size_t)BH * KP + kk]);

  const f32x4 ka0 = *(const f32x4*)(pK + off);
  const f32x4 ka1 = *(const f32x4*)(pK + off + 4);
  const f32x4 kb0 = *(const f32x4*)(pK + plane + off);
  const f32x4 kb1 = *(const f32x4*)(pK + plane + off + 4);
  const f32x4 va0 = *(const f32x4*)(pV + off);
  const f32x4 va1 = *(const f32x4*)(pV + off + 4);
  const f32x4 vb0 = *(const f32x4*)(pV + plane + off);
  const f32x4 vb1 = *(const f32x4*)(pV + plane + off + 4);
  const f32x4 K0  = *(const f32x4*)(Km + off);
  const f32x4 K1  = *(const f32x4*)(Km + off + 4);
  const f32x4 V0  = *(const f32x4*)(Vm + off);
  const f32x4 V1  = *(const f32x4*)(Vm + off + 4);

  f32x4 rk0 = (ka0 + kb0) * invr - K0;
  f32x4 rk1 = (ka1 + kb1) * invr - K1;
  f32x4 rv0 = (va0 + vb0) * invr - V0;
  f32x4 rv1 = (va1 + vb1) * invr - V1;

  *(f32x4*)(out + off)            = rk0;
  *(f32x4*)(out + off + 4)        = rk1;
  *(f32x4*)(out + GSZ + off)      = rv0;
  *(f32x4*)(out + GSZ + off + 4)  = rv1;
}

// ---------------------------------------------------------------------------
// Mid fallback: round-1 pass2 (proven, 114us) for ws in [NEED, NEED2).
// ---------------------------------------------------------------------------
__global__ __launch_bounds__(256) void hop_pass2m(
    const float* __restrict__ Km, const float* __restrict__ Vm,
    const bf16_t* __restrict__ xk16, const bf16_t* __restrict__ xkT16,
    const bf16_t* __restrict__ xvT16,
    const float* __restrict__ inv_colsum, float* __restrict__ out)
{
  __shared__ __align__(16) bf16_t xks[2][NT * DD];
  __shared__ __align__(16) bf16_t xkT[2][DD * NT];
  __shared__ __align__(16) bf16_t xvT[2][DD * NT];
  __shared__ __align__(16) bf16_t wt[4][16 * 72];

  const int tid  = threadIdx.x;
  const int wave = tid >> 6, lane = tid & 63;
  const int col  = lane & 15, quad = lane >> 4;
  const int bid  = blockIdx.x;
  const int bh   = (bid & 7) + 8 * ((bid >> 3) & 7);
  const int k0   = (bid >> 6) * 64 + wave * 16;

  const float*  Kb   = Km    + (size_t)bh * KP * DD;
  const float*  Vb   = Vm    + (size_t)bh * KP * DD;
  const bf16_t* xkb  = xk16  + (size_t)bh * NN * DD;
  const bf16_t* xkTb = xkT16 + (size_t)bh * DD * NN;
  const bf16_t* xvTb = xvT16 + (size_t)bh * DD * NN;
  const float*  inv  = inv_colsum + bh * NN;

  const bf16x8 ak0 = cvt8(Kb + (size_t)(k0 + col) * DD + quad * 8);
  const bf16x8 ak1 = cvt8(Kb + (size_t)(k0 + col) * DD + 32 + quad * 8);

  f32x4 accK[4], accV[4];
  #pragma unroll
  for (int i = 0; i < 4; i++) {
    accK[i] = (f32x4){0.f, 0.f, 0.f, 0.f};
    accV[i] = (f32x4){0.f, 0.f, 0.f, 0.f};
  }
  float rows_part = 0.f;

  const int srl = lane >> 3;
  const int r0  = wave * 16 + srl;
  const int r1  = r0 + 8;
  const int sb  = ((lane & 7) ^ srl) * 8;
  const int lb0 = (wave * 2 + 0) * 512;
  const int lb1 = (wave * 2 + 1) * 512;

  stage16(&xks[0][lb0], xkb + (size_t)r0 * DD + sb);
  stage16(&xks[0][lb1], xkb + (size_t)r1 * DD + sb);
  stage16(&xkT[0][lb0], xkTb + (size_t)r0 * NN + sb);
  stage16(&xkT[0][lb1], xkTb + (size_t)r1 * NN + sb);
  stage16(&xvT[0][lb0], xvTb + (size_t)r0 * NN + sb);
  stage16(&xvT[0][lb1], xvTb + (size_t)r1 * NN + sb);
  __syncthreads();

  int cur = 0;
  for (int n0 = 0; n0 < NN; n0 += NT) {
    if (n0 + NT < NN) {
      const int nx = n0 + NT;
      const int nb2 = cur ^ 1;
      stage16(&xks[nb2][lb0], xkb + (size_t)(nx + r0) * DD + sb);
      stage16(&xks[nb2][lb1], xkb + (size_t)(nx + r1) * DD + sb);
      stage16(&xkT[nb2][lb0], xkTb + (size_t)r0 * NN + nx + sb);
      stage16(&xkT[nb2][lb1], xkTb + (size_t)r1 * NN + nx + sb);
      stage16(&xvT[nb2][lb0], xvTb + (size_t)r0 * NN + nx + sb);
      stage16(&xvT[nb2][lb1], xvTb + (size_t)r1 * NN + nx + sb);
    }

    float ic[4];
    #pragma unroll
    for (int ns = 0; ns < 4; ns++) ic[ns] = inv[n0 + ns * 16 + col];

    const int key = col & 7;

    f32x4 s[4];
    #pragma unroll
    for (int ns = 0; ns < 4; ns++) {
      const bf16_t* bp = &xks[cur][(ns * 16 + col) * DD];
      const bf16x8 b0 = *(const bf16x8*)(bp + 8 * (quad ^ key));
      const bf16x8 b1 = *(const bf16x8*)(bp + 8 * ((quad + 4) ^ key));
      f32x4 c = {0.f, 0.f, 0.f, 0.f};
      c = MFMA16(ak0, b0, c);
      c = MFMA16(ak1, b1, c);
      s[ns] = c;
    }
    bf16_t* wr = wt[wave];
    #pragma unroll
    for (int ns = 0; ns < 4; ns++) {
      #pragma unroll
      for (int r = 0; r < 4; r++)
        wr[(quad * 4 + r) * 72 + ns * 16 + col] = (bf16_t)(__expf(s[ns][r]) * ic[ns]);
    }
    const bf16x8 wa0 = *(const bf16x8*)(wr + col * 72 + quad * 8);
    const bf16x8 wa1 = *(const bf16x8*)(wr + col * 72 + 32 + quad * 8);
    #pragma unroll
    for (int j = 0; j < 8; j++) rows_part += (float)wa0[j] + (float)wa1[j];

    #pragma unroll
    for (int dt = 0; dt < 4; dt++) {
      const int d = dt * 16 + col;
      const bf16_t* kp = &xkT[cur][d * NT];
      const bf16_t* vp = &xvT[cur][d * NT];
      const bf16x8 bk0 = *(const bf16x8*)(kp + 8 * (quad ^ key));
      const bf16x8 bk1 = *(const bf16x8*)(kp + 8 * ((quad + 4) ^ key));
      const bf16x8 bv0 = *(const bf16x8*)(vp + 8 * (quad ^ key));
      const bf16x8 bv1 = *(const bf16x8*)(vp + 8 * ((quad + 4) ^ key));
      accK[dt] = MFMA16(wa0, bk0, accK[dt]);
      accK[dt] = MFMA16(wa1, bk1, accK[dt]);
      accV[dt] = MFMA16(wa0, bv0, accV[dt]);
      accV[dt] = MFMA16(wa1, bv1, accV[dt]);
    }

    __syncthreads();
    cur ^= 1;
  }

  float rs = rows_part;
  rs += __shfl_xor(rs, 16, 64);
  rs += __shfl_xor(rs, 32, 64);
  float invrs[4];
  #pragma unroll
  for (int r = 0; r < 4; r++) invrs[r] = 1.0f / __shfl(rs, quad * 4 + r, 64);

  const size_t base = (size_t)bh * KP * DD;
  #pragma unroll
  for (int dt = 0; dt < 4; dt++) {
    #pragma unroll
    for (int r = 0; r < 4; r++) {
      const int k = k0 + quad * 4 + r;
      const int d = dt * 16 + col;
      const size_t idx = base + (size_t)k * DD + d;
      out[idx]       = accK[dt][r] * invrs[r] - Kb[(size_t)k * DD + d];
      out[GSZ + idx] = accV[dt][r] * invrs[r] - Vb[(size_t)k * DD + d];
    }
  }
}

// ---------------------------------------------------------------------------
// Fallback path (ws too small for bf16 scratch): round-0 verified kernels.
// ---------------------------------------------------------------------------
#define PW 72

__global__ __launch_bounds__(256) void hop_pass1_fb(
    const float* __restrict__ Km, const float* __restrict__ xk,
    float* __restrict__ inv_colsum)
{
  __shared__ __align__(16) bf16_t Ks[128 * 72];
  const int tid  = threadIdx.x;
  const int wave = tid >> 6, lane = tid & 63;
  const int col  = lane & 15, quad = lane >> 4;
  const int bh = blockIdx.y;
  const int n0 = blockIdx.x * 256 + wave * 64;
  const float* Kb  = Km + (size_t)bh * KP * DD;
  const float* xkb = xk + (size_t)bh * NN * DD;
  bf16x8 bf[4][2];
  #pragma unroll
  for (int nsub = 0; nsub < 4; nsub++) {
    const float* p = xkb + (size_t)(n0 + nsub * 16 + col) * DD + quad * 8;
    bf[nsub][0] = cvt8(p);
    bf[nsub][1] = cvt8(p + 32);
  }
  float colacc[4] = {0.f, 0.f, 0.f, 0.f};
  const int srow = tid >> 1, sdo = (tid & 1) * 32;
  for (int kc = 0; kc < KP; kc += 128) {
    __syncthreads();
    const float* src = Kb + (size_t)(kc + srow) * DD + sdo;
    #pragma unroll
    for (int u = 0; u < 4; u++) {
      const f32x4 p0 = *(const f32x4*)(src + 8 * u);
      const f32x4 p1 = *(const f32x4*)(src + 8 * u + 4);
      *(bf16x8*)(Ks + srow * 72 + sdo + 8 * u) = cvt8v(p0, p1);
    }
    __syncthreads();
    #pragma unroll
    for (int ks = 0; ks < 8; ks++) {
      const bf16x8 a0 = *(const bf16x8*)(Ks + (ks * 16 + col) * 72 + quad * 8);
      const bf16x8 a1 = *(const bf16x8*)(Ks + (ks * 16 + col) * 72 + 32 + quad * 8);
      #pragma unroll
      for (int nsub = 0; nsub < 4; nsub++) {
        f32x4 c = {0.f, 0.f, 0.f, 0.f};
        c = MFMA16(a0, bf[nsub][0], c);
        c = MFMA16(a1, bf[nsub][1], c);
        colacc[nsub] += __expf(c[0]) + __expf(c[1]) + __expf(c[2]) + __expf(c[3]);
      }
    }
  }
  #pragma unroll
  for (int nsub = 0; nsub < 4; nsub++) {
    colacc[nsub] += __shfl_xor(colacc[nsub], 16, 64);
    colacc[nsub] += __shfl_xor(colacc[nsub], 32, 64);
  }
  float v = colacc[0];
  v = (quad == 1) ? colacc[1] : v;
  v = (quad == 2) ? colacc[2] : v;
  v = (quad == 3) ? colacc[3] : v;
  inv_colsum[bh * NN + n0 + quad * 16 + col] = 1.0f / v;
}

__global__ __launch_bounds__(256) void hop_pass2_fb(
    const float* __restrict__ Km, const float* __restrict__ Vm,
    const float* __restrict__ xk, const float* __restrict__ xv,
    const float* __restrict__ inv_colsum, float* __restrict__ out)
{
  __shared__ __align__(16) bf16_t xksf[NT * PW];
  __shared__ __align__(16) bf16_t xkTf[DD * NT];
  __shared__ __align__(16) bf16_t xvTf[DD * NT];
  __shared__ __align__(16) bf16_t wtf[4][16 * PW];

  const int tid  = threadIdx.x;
  const int wave = tid >> 6, lane = tid & 63;
  const int col  = lane & 15, quad = lane >> 4;
  const int bh   = blockIdx.x >> 3;
  const int k0   = (blockIdx.x & 7) * 64 + wave * 16;

  const float* Kb  = Km + (size_t)bh * KP * DD;
  const float* Vb  = Vm + (size_t)bh * KP * DD;
  const float* xkb = xk + (size_t)bh * NN * DD;
  const float* xvb = xv + (size_t)bh * NN * DD;
  const float* inv = inv_colsum + bh * NN;

  const bf16x8 ak0 = cvt8(Kb + (size_t)(k0 + col) * DD + quad * 8);
  const bf16x8 ak1 = cvt8(Kb + (size_t)(k0 + col) * DD + 32 + quad * 8);

  f32x4 accK[4], accV[4];
  #pragma unroll
  for (int i = 0; i < 4; i++) {
    accK[i] = (f32x4){0.f, 0.f, 0.f, 0.f};
    accV[i] = (f32x4){0.f, 0.f, 0.f, 0.f};
  }
  float rows_part = 0.f;

  const int sn = tid >> 2;
  const int sd = (tid & 3) * 16;
  const int shi = sn >> 3, slo = sn & 7;

  for (int n0 = 0; n0 < NN; n0 += NT) {
    f32x4 gk[4], gv[4];
    #pragma unroll
    for (int u = 0; u < 4; u++) {
      gk[u] = *(const f32x4*)(xkb + (size_t)(n0 + sn) * DD + sd + 4 * u);
      gv[u] = *(const f32x4*)(xvb + (size_t)(n0 + sn) * DD + sd + 4 * u);
    }
    float ic[4];
    #pragma unroll
    for (int nsub = 0; nsub < 4; nsub++) ic[nsub] = inv[n0 + nsub * 16 + col];

    __syncthreads();
    *(bf16x8*)(xksf + sn * PW + sd)     = cvt8v(gk[0], gk[1]);
    *(bf16x8*)(xksf + sn * PW + sd + 8) = cvt8v(gk[2], gk[3]);
    #pragma unroll
    for (int j = 0; j < 16; j++) {
      const int d   = sd + j;
      const int off = d * NT + (((shi) ^ (d >> 3)) << 3) + slo;
      xkTf[off] = (bf16_t)gk[j >> 2][j & 3];
      xvTf[off] = (bf16_t)gv[j >> 2][j & 3];
    }
    __syncthreads();

    f32x4 s[4];
    #pragma unroll
    for (int nsub = 0; nsub < 4; nsub++) {
      const bf16x8 b0 = *(const bf16x8*)(xksf + (nsub * 16 + col) * PW + quad * 8);
      const bf16x8 b1 = *(const bf16x8*)(xksf + (nsub * 16 + col) * PW + 32 + quad * 8);
      f32x4 c = {0.f, 0.f, 0.f, 0.f};
      c = MFMA16(ak0, b0, c);
      c = MFMA16(ak1, b1, c);
      s[nsub] = c;
    }
    bf16_t* wr = wtf[wave];
    #pragma unroll
    for (int nsub = 0; nsub < 4; nsub++) {
      #pragma unroll
      for (int r = 0; r < 4; r++)
        wr[(quad * 4 + r) * PW + nsub * 16 + col] = (bf16_t)(__expf(s[nsub][r]) * ic[nsub]);
    }
    const bf16x8 wa0 = *(const bf16x8*)(wr + col * PW + quad * 8);
    const bf16x8 wa1 = *(const bf16x8*)(wr + col * PW + 32 + quad * 8);
    #pragma unroll
    for (int j = 0; j < 8; j++) rows_part += (float)wa0[j] + (float)wa1[j];

    #pragma unroll
    for (int dt = 0; dt < 4; dt++) {
      const int d = dt * 16 + col, dhi = d >> 3;
      const bf16x8 bk0 = *(const bf16x8*)(xkTf + d * NT + ((quad ^ dhi) << 3));
      const bf16x8 bk1 = *(const bf16x8*)(xkTf + d * NT + (((4 + quad) ^ dhi) << 3));
      const bf16x8 bv0 = *(const bf16x8*)(xvTf + d * NT + ((quad ^ dhi) << 3));
      const bf16x8 bv1 = *(const bf16x8*)(xvTf + d * NT + (((4 + quad) ^ dhi) << 3));
      accK[dt] = MFMA16(wa0, bk0, accK[dt]);
      accK[dt] = MFMA16(wa1, bk1, accK[dt]);
      accV[dt] = MFMA16(wa0, bv0, accV[dt]);
      accV[dt] = MFMA16(wa1, bv1, accV[dt]);
    }
  }

  float rs = rows_part;
  rs += __shfl_xor(rs, 16, 64);
  rs += __shfl_xor(rs, 32, 64);
  float invrs[4];
  #pragma unroll
  for (int r = 0; r < 4; r++) invrs[r] = 1.0f / __shfl(rs, quad * 4 + r, 64);

  const size_t base = (size_t)bh * KP * DD;
  #pragma unroll
  for (int dt = 0; dt < 4; dt++) {
    #pragma unroll
    for (int r = 0; r < 4; r++) {
      const int k = k0 + quad * 4 + r;
      const int d = dt * 16 + col;
      const size_t idx = base + (size_t)k * DD + d;
      out[idx]       = accK[dt][r] * invrs[r] - Kb[(size_t)k * DD + d];
      out[GSZ + idx] = accV[dt][r] * invrs[r] - Vb[(size_t)k * DD + d];
    }
  }
}

extern "C" void kernel_launch(void* const* d_in, const int* in_sizes, int n_in,
                              void* d_out, int out_size, void* d_ws, size_t ws_size,
                              hipStream_t stream)
{
  (void)in_sizes; (void)n_in; (void)out_size;
  const float* Km = (const float*)d_in[0];
  const float* Vm = (const float*)d_in[1];
  const float* xk = (const float*)d_in[2];
  const float* xv = (const float*)d_in[3];
  float* out = (float*)d_out;

  const size_t INVB = (size_t)BH * NN * sizeof(float);          // 1 MB
  const size_t SCRE = (size_t)BH * NN * DD;                     // bf16 elems per array
  const size_t NEED  = INVB + 3 * SCRE * sizeof(bf16_t);        // ~101.7 MB
  const size_t PPART = (size_t)2 * BH * KP * DD;                // f32 elems per partial
  const size_t NEED2 = NEED + (2 * PPART + (size_t)2 * BH * KP) * sizeof(float); // ~135.5 MB

  float* inv_colsum = (float*)d_ws;

  if (ws_size >= NEED2) {
    bf16_t* xk16  = (bf16_t*)((char*)d_ws + INVB);
    bf16_t* xkT16 = xk16 + SCRE;
    bf16_t* xvT16 = xkT16 + SCRE;
    float*  pK    = (float*)(xvT16 + SCRE);
    float*  pV    = pK + PPART;
    float*  prs   = pV + PPART;
    hop_prep<<<dim3(NN / 64, BH), 256, 0, stream>>>(xk, xv, xk16, xkT16, xvT16);
    hop_pass1<<<dim3((NN / 256) * BH), 256, 0, stream>>>(Km, xk16, inv_colsum);
    hop_pass2s<<<dim3(512), 256, 0, stream>>>(Km, xk16, xkT16, xvT16,
                                              inv_colsum, pK, pV, prs);
    hop_fin<<<dim3((BH * KP * DD) / (256 * 8)), 256, 0, stream>>>(Km, Vm, pK, pV,
                                                                  prs, out);
  } else if (ws_size >= NEED) {
    bf16_t* xk16  = (bf16_t*)((char*)d_ws + INVB);
    bf16_t* xkT16 = xk16 + SCRE;
    bf16_t* xvT16 = xkT16 + SCRE;
    hop_prep<<<dim3(NN / 64, BH), 256, 0, stream>>>(xk, xv, xk16, xkT16, xvT16);
    hop_pass1<<<dim3((NN / 256) * BH), 256, 0, stream>>>(Km, xk16, inv_colsum);
    hop_pass2m<<<dim3(BH * (KP / 64)), 256, 0, stream>>>(Km, Vm, xk16, xkT16, xvT16,
                                                         inv_colsum, out);
  } else {
    hop_pass1_fb<<<dim3(NN / 256, BH), 256, 0, stream>>>(Km, xk, inv_colsum);
    hop_pass2_fb<<<dim3(BH * (KP / 64)), 256, 0, stream>>>(Km, Vm, xk, xv,
                                                           inv_colsum, out);
  }
}